// Round 10
// baseline (189.424 us; speedup 1.0000x reference)
//
#include <hip/hip_runtime.h>

#define B_ 2
#define H_ 16
#define T_ 2048
#define D_ 1024
#define HD_ 64
#define NEG_HUGE (-3.402823466e38f)
#define QSCALE 0.18033688011112042f   // 0.125 * log2(e), folded into Q projection

typedef unsigned short u16;
typedef unsigned int u32;
typedef __attribute__((ext_vector_type(8))) short bf16x8;
typedef __attribute__((ext_vector_type(4))) float f32x4;
typedef __attribute__((ext_vector_type(4))) u32 u32x4;

typedef const __attribute__((address_space(1))) void* gas_t;
typedef __attribute__((address_space(3))) void* las_t;

__device__ __forceinline__ u16 f2bf(float f) {
    u32 u = __builtin_bit_cast(u32, f);
    u += 0x7FFFu + ((u >> 16) & 1u);      // RNE
    return (u16)(u >> 16);
}

// pack 2 f32 -> 2 bf16 (round-half-up) in one v_perm_b32
__device__ __forceinline__ u32 pk2bf(float f0, float f1) {
    const u32 a0 = __builtin_bit_cast(u32, f0) + 0x8000u;
    const u32 a1 = __builtin_bit_cast(u32, f1) + 0x8000u;
    return __builtin_amdgcn_perm(a1, a0, 0x07060302u);
}

// pack 2 f32 -> 2 bf16 (RNE) in ONE instruction (gfx950 native)
__device__ __forceinline__ u32 cvtpk2bf(float f0, float f1) {
    u32 r;
    asm("v_cvt_pk_bf16_f32 %0, %1, %2" : "=v"(r) : "v"(f0), "v"(f1));
    return r;   // lo = bf16(f0), hi = bf16(f1)
}

__device__ __forceinline__ uint2 pk4bf(f32x4 a) {
    uint2 r;
    r.x = pk2bf(a[0], a[1]);
    r.y = pk2bf(a[2], a[3]);
    return r;
}

__device__ __forceinline__ f32x4 mfma16(bf16x8 a, bf16x8 b, f32x4 c) {
    return __builtin_amdgcn_mfma_f32_16x16x32_bf16(a, b, c, 0, 0, 0);
}

// fp32 -> bf16 cast of concat [x(4M) | Wq(1M) | Wk(1M) | Wv(1M) | Wo(1M)] elems
__global__ __launch_bounds__(256) void to_bf16(
    const float* __restrict__ x,  const float* __restrict__ wq,
    const float* __restrict__ wk, const float* __restrict__ wv,
    const float* __restrict__ wo, u16* __restrict__ dst)
{
    const size_t g = ((size_t)blockIdx.x * 256 + threadIdx.x) * 8;
    const float* src; size_t off;
    if      (g < (size_t)(4u << 20)) { src = x;  off = g; }
    else if (g < (size_t)(5u << 20)) { src = wq; off = g - (size_t)(4u << 20); }
    else if (g < (size_t)(6u << 20)) { src = wk; off = g - (size_t)(5u << 20); }
    else if (g < (size_t)(7u << 20)) { src = wv; off = g - (size_t)(6u << 20); }
    else                             { src = wo; off = g - (size_t)(7u << 20); }
    const float4 a = *(const float4*)&src[off];
    const float4 b = *(const float4*)&src[off + 4];
    ushort4 lo = make_ushort4(f2bf(a.x), f2bf(a.y), f2bf(a.z), f2bf(a.w));
    ushort4 hi = make_ushort4(f2bf(b.x), f2bf(b.y), f2bf(b.z), f2bf(b.w));
    *(ushort4*)&dst[g]     = lo;
    *(ushort4*)&dst[g + 4] = hi;
}

// 128x128x1024 bf16 MFMA core with REGISTER-prefetch staging (gemm_out):
// loads stay in flight across the barrier covering L2 latency.
__device__ __forceinline__ void gemm128_core(
    const u16* __restrict__ P0, const u16* __restrict__ P1,
    const int m0, const int n0, u16* As, u16* Bs, f32x4 (&acc)[4][4])
{
    const int tid  = threadIdx.x;
    const int lane = tid & 63;
    const int quad = lane >> 4;
    const int l15  = lane & 15;
    const int w    = tid >> 6;
    const int wm   = (w >> 1) << 6;
    const int wn   = (w & 1) << 6;
    const int swz  = l15 & 7;

    size_t aoff[4], boff[4];
    int    loff[4];
#pragma unroll
    for (int i = 0; i < 4; ++i) {
        const int slot = i * 256 + tid;
        const int r = slot >> 3, c = slot & 7;
        const int gc = (c ^ (r & 7)) << 3;
        aoff[i] = (size_t)(m0 + r) * D_ + gc;
        boff[i] = (size_t)(n0 + r) * D_ + gc;
        loff[i] = slot * 8;
    }
    int rowA[4], rowB[4];
#pragma unroll
    for (int i = 0; i < 4; ++i) {
        rowA[i] = (wm + i * 16 + l15) * 64;
        rowB[i] = (wn + i * 16 + l15) * 64;
    }

    bf16x8 pa[4], pb[4];
#pragma unroll
    for (int i = 0; i < 4; ++i) {
        pa[i] = *(const bf16x8*)&P0[aoff[i]];
        pb[i] = *(const bf16x8*)&P1[boff[i]];
    }

    for (int k0 = 0; k0 < D_; k0 += 64) {
        __syncthreads();                  // prev compute done reading LDS
#pragma unroll
        for (int i = 0; i < 4; ++i) {
            *(bf16x8*)&As[loff[i]] = pa[i];
            *(bf16x8*)&Bs[loff[i]] = pb[i];
        }
        if (k0 + 64 < D_) {
            const int kn = k0 + 64;
#pragma unroll
            for (int i = 0; i < 4; ++i) {
                pa[i] = *(const bf16x8*)&P0[aoff[i] + kn];
                pb[i] = *(const bf16x8*)&P1[boff[i] + kn];
            }
        }
        __syncthreads();                  // staging visible; prefetch in flight
#pragma unroll
        for (int s = 0; s < 2; ++s) {
            const int ch = (((s << 2) + quad) ^ swz) << 3;
            bf16x8 am[4], bm[4];
#pragma unroll
            for (int mi = 0; mi < 4; ++mi) am[mi] = *(const bf16x8*)&As[rowA[mi] + ch];
#pragma unroll
            for (int ni = 0; ni < 4; ++ni) bm[ni] = *(const bf16x8*)&Bs[rowB[ni] + ch];
#pragma unroll
            for (int mi = 0; mi < 4; ++mi)
#pragma unroll
                for (int ni = 0; ni < 4; ++ni)
                    acc[mi][ni] = mfma16(am[mi], bm[ni], acc[mi][ni]);
        }
    }
}

// Fused QKV projection as ONE 3072x4096x1024 GEMM. 256^2 tiles, 512 thr
// (8 waves 2Mx4N), 128 KiB LDS double-buffered by K-tile, global_load_lds
// width-16 staging with COUNTED vmcnt (never drained to 0 mid-loop) and
// raw s_barrier. TWO phases per K-tile (best of 4 structures measured).
__global__ __launch_bounds__(512, 2) void gemm_qkv(
    const u16* __restrict__ xb,
    const u16* __restrict__ Wqb, const u16* __restrict__ Wkb, const u16* __restrict__ Wvb,
    const float* __restrict__ bq, const float* __restrict__ bk, const float* __restrict__ bv,
    u16* __restrict__ Qb, u16* __restrict__ Kb, u16* __restrict__ Vtb)
{
    __shared__ u16 lds[65536];            // 128 KiB: [A0|A1|B0|B1] 16K elems each
    const int tid  = threadIdx.x;
    const int lane = tid & 63;
    const int quad = lane >> 4;
    const int l15  = lane & 15;
    const int w    = tid >> 6;
    const int wr   = w >> 2;              // 0..1 (M dir)
    const int wc   = w & 3;               // 0..3 (N dir)
    const int swz7 = l15 & 7;

    const int L  = blockIdx.x;
    const int wg = (L & 7) * 24 + (L >> 3);   // bijective XCD swizzle (192%8==0)
    const int ftile = wg >> 4;            // 0..11
    const int ttile = wg & 15;            // 0..15
    const int z  = ftile >> 2;            // 0:Q 1:K 2:V
    const int fb = (ftile & 3) << 8;      // feature base within 1024

    const u16* PA; const u16* PB;
    int Ra, Rb;
    if (z == 0)      { PA = Wqb; PB = xb;  Ra = fb;         Rb = ttile << 8; }
    else if (z == 1) { PA = Wkb; PB = xb;  Ra = fb;         Rb = ttile << 8; }
    else             { PA = xb;  PB = Wvb; Ra = ttile << 8; Rb = fb;         }

    // staging addresses: load i covers rows [i*64, i*64+64) of the 256-row side
    const int rr  = tid >> 3;
    const int cc8 = ((tid & 7) ^ (rr & 7)) << 3;   // pre-swizzled source chunk
    size_t srcA[4], srcB[4];
#pragma unroll
    for (int i = 0; i < 4; ++i) {
        srcA[i] = (size_t)(Ra + i * 64 + rr) * D_ + cc8;
        srcB[i] = (size_t)(Rb + i * 64 + rr) * D_ + cc8;
    }
    const int dstT = tid * 8;             // linear LDS dest (elems), lane*16B

#define QKV_STAGE(p, kt) do {                                               \
    const size_t ko_ = (size_t)(kt) * 64;                                   \
    _Pragma("unroll")                                                       \
    for (int i_ = 0; i_ < 4; ++i_)                                          \
        __builtin_amdgcn_global_load_lds((gas_t)(PA + srcA[i_] + ko_),      \
            (las_t)&lds[((p) << 14) + i_ * 4096 + dstT], 16, 0, 0);         \
    _Pragma("unroll")                                                       \
    for (int i_ = 0; i_ < 4; ++i_)                                          \
        __builtin_amdgcn_global_load_lds((gas_t)(PB + srcB[i_] + ko_),      \
            (las_t)&lds[32768 + ((p) << 14) + i_ * 4096 + dstT], 16, 0, 0); \
} while (0)

    // fragment read bases (r&7 == l15&7 for all mi/ni since 16|step)
    const int baseA = ((wr << 7) + l15) * 64;
    const int baseB = 32768 + ((wc << 6) + l15) * 64;
    const int cs0 = (quad ^ swz7) << 3;
    const int cs1 = ((quad + 4) ^ swz7) << 3;

    f32x4 acc[8][4];
#pragma unroll
    for (int i = 0; i < 8; ++i)
#pragma unroll
        for (int j = 0; j < 4; ++j) acc[i][j] = (f32x4){0.f, 0.f, 0.f, 0.f};

    QKV_STAGE(0, 0);
    QKV_STAGE(1, 1);
    asm volatile("s_waitcnt vmcnt(8)" ::: "memory");   // K-tile 0 landed
    __builtin_amdgcn_s_barrier();

    for (int kt = 0; kt < 16; ++kt) {
        const int pO = (kt & 1) << 14;
        bf16x8 bfr[4][2], afr[4][2];
#pragma unroll
        for (int ni = 0; ni < 4; ++ni) {
            bfr[ni][0] = *(const bf16x8*)&lds[pO + baseB + ni * 1024 + cs0];
            bfr[ni][1] = *(const bf16x8*)&lds[pO + baseB + ni * 1024 + cs1];
        }
#pragma unroll
        for (int mi = 0; mi < 4; ++mi) {
            afr[mi][0] = *(const bf16x8*)&lds[pO + baseA + mi * 1024 + cs0];
            afr[mi][1] = *(const bf16x8*)&lds[pO + baseA + mi * 1024 + cs1];
        }
        __builtin_amdgcn_s_setprio(1);
#pragma unroll
        for (int mi = 0; mi < 4; ++mi)
#pragma unroll
            for (int ni = 0; ni < 4; ++ni) {
                acc[mi][ni] = mfma16(afr[mi][0], bfr[ni][0], acc[mi][ni]);
                acc[mi][ni] = mfma16(afr[mi][1], bfr[ni][1], acc[mi][ni]);
            }
        __builtin_amdgcn_s_setprio(0);
#pragma unroll
        for (int mi = 0; mi < 4; ++mi) {
            afr[mi][0] = *(const bf16x8*)&lds[pO + baseA + (mi + 4) * 1024 + cs0];
            afr[mi][1] = *(const bf16x8*)&lds[pO + baseA + (mi + 4) * 1024 + cs1];
        }
        asm volatile("s_waitcnt lgkmcnt(0)" ::: "memory");  // all my LDS reads done
        __builtin_amdgcn_sched_barrier(0);
        __builtin_amdgcn_s_barrier();                       // buf(kt&1) free
        __builtin_amdgcn_sched_barrier(0);
        if (kt + 2 < 16) QKV_STAGE(kt & 1, kt + 2);         // overwrite freed buf
        __builtin_amdgcn_s_setprio(1);
#pragma unroll
        for (int mi = 0; mi < 4; ++mi)
#pragma unroll
            for (int ni = 0; ni < 4; ++ni) {
                acc[mi + 4][ni] = mfma16(afr[mi][0], bfr[ni][0], acc[mi + 4][ni]);
                acc[mi + 4][ni] = mfma16(afr[mi][1], bfr[ni][1], acc[mi + 4][ni]);
            }
        __builtin_amdgcn_s_setprio(0);
        if (kt < 14) asm volatile("s_waitcnt vmcnt(8)" ::: "memory"); // tile kt+1 in
        else         asm volatile("s_waitcnt vmcnt(0)" ::: "memory"); // tail drain
        __builtin_amdgcn_sched_barrier(0);
        __builtin_amdgcn_s_barrier();                       // buf(kt+1 & 1) ready
    }
#undef QKV_STAGE

    __syncthreads();                      // LDS reusable as epilogue scratch
    u16* scr = &lds[w * 8192];            // 16 KB per wave
    const int pq   = quad >> 1;
    const int psub = (quad & 1) << 2;

    if (z < 2) {
        // wave tile: f [fb+wr*128, +128) (2 heads), t [ttile*256+wc*64, +64)
        const float* bias = (z == 0) ? bq : bk;
        const float  CF   = (z == 0) ? QSCALE : 1.f;
        u16*         Cq   = (z == 0) ? Qb : Kb;
        const int fbw = fb + (wr << 7);
        const int tbw = (ttile << 8) + (wc << 6);
        // scratch [t 64][f 128], 16-chunk XOR swizzle
#pragma unroll
        for (int mi = 0; mi < 8; ++mi) {
            const float4 bi = *(const float4*)&bias[fbw + mi * 16 + (quad << 2)];
            const int c = (mi << 1) + pq;
#pragma unroll
            for (int ni = 0; ni < 4; ++ni) {
                const int tl = ni * 16 + l15;
                f32x4 a = acc[mi][ni];
                f32x4 v = { (a[0] + bi.x) * CF, (a[1] + bi.y) * CF,
                            (a[2] + bi.z) * CF, (a[3] + bi.w) * CF };
                *(uint2*)&scr[tl * 128 + ((c ^ (tl & 15)) << 3) + psub] = pk4bf(v);
            }
        }
        __asm__ volatile("s_waitcnt lgkmcnt(0)" ::: "memory");
        const int hb = fbw >> 6;
#pragma unroll
        for (int e = 0; e < 16; ++e) {
            const int tl = (e << 2) + (lane >> 4);
            const int c  = lane & 15;
            bf16x8 v = *(const bf16x8*)&scr[tl * 128 + ((c ^ (tl & 15)) << 3)];
            const int tg = tbw + tl;
            const int bb = tg >> 11, t0 = tg & 2047;
            *(bf16x8*)&Cq[((size_t)((bb << 4) + hb + (c >> 3)) * T_ + t0) * HD_ +
                          ((c & 7) << 3)] = v;
        }
    } else {
        // V: M=t, N=f. wave tile: t [ttile*256+wr*128, +128), f [fb+wc*64, +64)
        const int fvw = fb + (wc << 6);
        const int h   = fvw >> 6;
        const int tbw = (ttile << 8) + (wr << 7);
        // scratch [hd 64][t 128]
#pragma unroll
        for (int ni = 0; ni < 4; ++ni) {
            const int hdrow = ni * 16 + l15;
            const float bi = bv[fvw + ni * 16 + l15];
            const int sw = hdrow & 15;
#pragma unroll
            for (int mi = 0; mi < 8; ++mi) {
                f32x4 a = acc[mi][ni];
                f32x4 v = { a[0] + bi, a[1] + bi, a[2] + bi, a[3] + bi };
                const int c = (mi << 1) + pq;
                *(uint2*)&scr[hdrow * 128 + ((c ^ sw) << 3) + psub] = pk4bf(v);
            }
        }
        __asm__ volatile("s_waitcnt lgkmcnt(0)" ::: "memory");
#pragma unroll
        for (int e = 0; e < 16; ++e) {
            const int hdl = (e << 2) + (lane >> 4);
            const int c   = lane & 15;
            bf16x8 v = *(const bf16x8*)&scr[hdl * 128 + ((c ^ (hdl & 15)) << 3)];
            const int tg = tbw + (c << 3);
            const int bb = tg >> 11, t0 = tg & 2047;
            *(bf16x8*)&Vtb[((size_t)((bb << 4) + h) * HD_ + hdl) * T_ + t0] = v;
        }
    }
}

// Output projection: A bf16 (B,T,D), W bf16, C fp32 + bias. XCD-swizzled.
// Reg-staged 128^2 core (r4-proven).
__global__ __launch_bounds__(256) void gemm_out(
    const u16* __restrict__ Ab, const u16* __restrict__ Wob,
    const float* __restrict__ bo, float* __restrict__ C)
{
    __shared__ u16 As[128 * 64];
    __shared__ u16 Bs[128 * 64];
    const int L   = blockIdx.x;
    const int xcd = L & 7;
    const int kk  = L >> 3;               // 0..31
    const int tt  = (xcd << 2) + (kk & 3);
    const int ft  = kk >> 2;              // 0..7
    const int m0  = tt << 7;
    const int n0  = ft << 7;

    f32x4 acc[4][4];
#pragma unroll
    for (int i = 0; i < 4; ++i)
#pragma unroll
        for (int j = 0; j < 4; ++j) acc[i][j] = (f32x4){0.f, 0.f, 0.f, 0.f};

    gemm128_core(Ab, Wob, m0, n0, As, Bs, acc);

    const int tid  = threadIdx.x;
    const int lane = tid & 63;
    const int quad = lane >> 4;
    const int l15  = lane & 15;
    const int w    = tid >> 6;
    const int wm   = (w >> 1) << 6;
    const int wn   = (w & 1) << 6;

    float bi[4];
#pragma unroll
    for (int ni = 0; ni < 4; ++ni) bi[ni] = bo[n0 + wn + ni * 16 + l15];

#pragma unroll
    for (int mi = 0; mi < 4; ++mi) {
        const int m = m0 + wm + mi * 16 + (quad << 2);
#pragma unroll
        for (int r = 0; r < 4; ++r)
#pragma unroll
            for (int ni = 0; ni < 4; ++ni)
                C[(size_t)(m + r) * D_ + n0 + wn + ni * 16 + l15] = acc[mi][ni][r] + bi[ni];
    }
}

// MFMA flash attention, causal, 128-key pipelined tiles, MAX-FREE softmax
// (base-2 scores, scale folded into Q). Grid (B*H, 32), one 64-row q-tile
// per block, LPT order.
//
// 2x2 (q x key) WAVE DECOMPOSITION: wave (qw, kw) owns q-rows [qw*32,+32)
// x keys [kw*64,+64) of each 128-key tile. Cuts per-iter LDS reads from
// 128 KB (every wave read full K and V tiles) to 64 KB — the kernel is
// LDS-BW-bound (160 KB/iter @ 256 B/clk = 625 cyc ~= measured ~650
// cyc/iter), which is why occupancy (r3) and dbuf (r7) probes were null.
// Each wave accumulates partial O (32q x 64d) + L over its key-half;
// one pairwise LDS reduction (kw=1 writes 16 KB overlay, barrier, kw=0
// adds) finalizes. P stays in registers (cvt_pk + permlane transpose).
__global__ __launch_bounds__(256) void attn_mfma(
    const u16* __restrict__ Qg, const u16* __restrict__ Kg,
    const u16* __restrict__ Vtg, u16* __restrict__ Out)
{
    __shared__ u16 Ks[128 * 64];     // [key][hd], XOR-swizzled; f32 O-reduce overlay
    __shared__ u16 Vs[64 * 128];     // [hd][key], XOR-swizzled; f32 L-reduce overlay
    const int tid  = threadIdx.x;
    const int w    = tid >> 6;
    const int lane = tid & 63;
    const int quad = lane >> 4;
    const int l15  = lane & 15;
    const int bh   = blockIdx.x;
    const int qt   = 31 - (int)blockIdx.y;         // longest first
    const size_t base = (size_t)bh * (T_ * HD_);

    const int qw   = w >> 1;         // q half: rows [qw*32, +32)
    const int kw   = w & 1;          // key half: keys [kw*64, +64)
    const int wkey = kw << 6;

    int lK[4], lV[4];
    size_t gK[4], gV[4];
#pragma unroll
    for (int i = 0; i < 4; ++i) {
        const int slot = i * 256 + tid;
        const int rk = slot >> 3, ck = slot & 7;
        lK[i] = rk * 64 + ((ck ^ (rk & 7)) << 3);
        gK[i] = base + (size_t)rk * HD_ + ck * 8;
        const int rv = slot >> 4, cv = slot & 15;
        lV[i] = rv * 128 + ((cv ^ (rv & 15)) << 3);
        gV[i] = base + (size_t)rv * T_ + cv * 8;
    }

    bf16x8 ones;
#pragma unroll
    for (int i = 0; i < 8; ++i) ones[i] = (short)0x3F80;   // bf16 1.0

    const int swz7 = l15 & 7;
    const int b = bh >> 4, h = bh & 15;

    // Wave's 32 q-rows in registers as B-operand frags (2 blocks x 2 halves)
    bf16x8 qf[2][2];
#pragma unroll
    for (int j = 0; j < 2; ++j) {
        const size_t qoff =
            base + (size_t)((qt << 6) + (qw << 5) + j * 16 + l15) * HD_ + quad * 8;
        qf[j][0] = *(const bf16x8*)&Qg[qoff];
        qf[j][1] = *(const bf16x8*)&Qg[qoff + 32];
    }

    f32x4 o[2][4];     // [j][nt]: q = qw*32+j*16+quad*4+r, d = nt*16+l15 (partial)
#pragma unroll
    for (int j = 0; j < 2; ++j)
#pragma unroll
        for (int nt = 0; nt < 4; ++nt) o[j][nt] = (f32x4){0.f, 0.f, 0.f, 0.f};
    f32x4 Lacc[2];     // [j]: L[q = qw*32+j*16+quad*4+r] partial
    Lacc[0] = (f32x4){0.f, 0.f, 0.f, 0.f};
    Lacc[1] = (f32x4){0.f, 0.f, 0.f, 0.f};

    const int nIter = (qt + 2) >> 1;
    bf16x8 kreg[4], vreg[4];
#pragma unroll
    for (int i = 0; i < 4; ++i) {
        kreg[i] = *(const bf16x8*)&Kg[gK[i]];
        vreg[i] = *(const bf16x8*)&Vtg[gV[i]];
    }

    for (int it = 0; it < nIter; ++it) {
        __syncthreads();
#pragma unroll
        for (int i = 0; i < 4; ++i) {
            *(bf16x8*)&Ks[lK[i]] = kreg[i];
            *(bf16x8*)&Vs[lV[i]] = vreg[i];
        }
        if (it + 1 < nIter) {
            const int koff = (it + 1) << 7;
#pragma unroll
            for (int i = 0; i < 4; ++i) {
                kreg[i] = *(const bf16x8*)&Kg[gK[i] + (size_t)koff * HD_];
                vreg[i] = *(const bf16x8*)&Vtg[gV[i] + koff];
            }
        }
        __syncthreads();

        // QK^T: wave's 4 key m-tiles x 2 q-blocks; K frags shared across j
        f32x4 st[4][2];
#pragma unroll
        for (int mt = 0; mt < 4; ++mt) {
            const int kr = (wkey + mt * 16 + l15) * 64;
            const bf16x8 k0 = *(const bf16x8*)&Ks[kr + ((quad ^ swz7) << 3)];
            const bf16x8 k1 = *(const bf16x8*)&Ks[kr + (((quad + 4) ^ swz7) << 3)];
#pragma unroll
            for (int j = 0; j < 2; ++j) {
                f32x4 a = (f32x4){0.f, 0.f, 0.f, 0.f};
                a = mfma16(k0, qf[j][0], a);
                a = mfma16(k1, qf[j][1], a);
                st[mt][j] = a;
            }
        }

        if (it == nIter - 1) {
            const int kb = (it << 7) + wkey;
#pragma unroll
            for (int mt = 0; mt < 4; ++mt)
#pragma unroll
                for (int r = 0; r < 4; ++r) {
                    const int kg = kb + mt * 16 + (quad << 2) + r;
#pragma unroll
                    for (int j = 0; j < 2; ++j) {
                        const int qg = (qt << 6) + (qw << 5) + j * 16 + l15;
                        if (kg > qg) st[mt][j][r] = NEG_HUGE;
                    }
                }
        }

#pragma unroll
        for (int mt = 0; mt < 4; ++mt)
#pragma unroll
            for (int j = 0; j < 2; ++j)
#pragma unroll
                for (int r = 0; r < 4; ++r)
                    st[mt][j][r] = __builtin_amdgcn_exp2f(st[mt][j][r]);

        // transpose P: per (kq 32-key group, j) -> A-frags over 32 keys
        bf16x8 pf[2][2];   // [kq][j]
#pragma unroll
        for (int kq = 0; kq < 2; ++kq)
#pragma unroll
            for (int j = 0; j < 2; ++j) {
                u32 c00 = cvtpk2bf(st[2 * kq][j][0],     st[2 * kq][j][1]);
                u32 c01 = cvtpk2bf(st[2 * kq][j][2],     st[2 * kq][j][3]);
                u32 c10 = cvtpk2bf(st[2 * kq + 1][j][0], st[2 * kq + 1][j][1]);
                u32 c11 = cvtpk2bf(st[2 * kq + 1][j][2], st[2 * kq + 1][j][3]);
                asm("v_permlane32_swap_b32 %0, %1" : "+v"(c00), "+v"(c10));
                asm("v_permlane16_swap_b32 %0, %1" : "+v"(c00), "+v"(c10));
                asm("v_permlane32_swap_b32 %0, %1" : "+v"(c01), "+v"(c11));
                asm("v_permlane16_swap_b32 %0, %1" : "+v"(c01), "+v"(c11));
                u32x4 dw;
                dw[0] = c00; dw[1] = c01; dw[2] = c10; dw[3] = c11;
                pf[kq][j] = __builtin_bit_cast(bf16x8, dw);
            }

        __builtin_amdgcn_s_setprio(1);
#pragma unroll
        for (int nt = 0; nt < 4; ++nt) {
            const int vr = (nt * 16 + l15) * 128;
#pragma unroll
            for (int kq = 0; kq < 2; ++kq) {
                const bf16x8 vf = *(const bf16x8*)
                    &Vs[vr + ((((kw << 3) + (kq << 2) + quad) ^ l15) << 3)];
#pragma unroll
                for (int j = 0; j < 2; ++j)
                    o[j][nt] = mfma16(pf[kq][j], vf, o[j][nt]);
            }
        }
#pragma unroll
        for (int kq = 0; kq < 2; ++kq)
#pragma unroll
            for (int j = 0; j < 2; ++j)
                Lacc[j] = mfma16(pf[kq][j], ones, Lacc[j]);
        __builtin_amdgcn_s_setprio(0);
    }

    // Pairwise cross-wave reduction over the key split (kw=1 -> kw=0).
    __syncthreads();                    // all waves done reading Ks/Vs
    float* Rf = (float*)Ks;             // [qw][32 q][64 d] f32 = 16 KB
    float* Lf = (float*)Vs;             // [64 q] f32
    if (kw == 1) {
#pragma unroll
        for (int j = 0; j < 2; ++j) {
#pragma unroll
            for (int nt = 0; nt < 4; ++nt)
#pragma unroll
                for (int r = 0; r < 4; ++r)
                    Rf[(qw << 11) + (j * 16 + (quad << 2) + r) * 64 + nt * 16 + l15]
                        = o[j][nt][r];
            if (l15 == 0) {
#pragma unroll
                for (int r = 0; r < 4; ++r)
                    Lf[(qw << 5) + j * 16 + (quad << 2) + r] = Lacc[j][r];
            }
        }
    }
    __syncthreads();
    if (kw == 0) {
#pragma unroll
        for (int j = 0; j < 2; ++j) {
#pragma unroll
            for (int nt = 0; nt < 4; ++nt)
#pragma unroll
                for (int r = 0; r < 4; ++r)
                    o[j][nt][r] +=
                        Rf[(qw << 11) + (j * 16 + (quad << 2) + r) * 64 + nt * 16 + l15];
#pragma unroll
            for (int r = 0; r < 4; ++r)
                Lacc[j][r] += Lf[(qw << 5) + j * 16 + (quad << 2) + r];
        }

        // Output: kw=0 waves store their 32 q-rows
#pragma unroll
        for (int j = 0; j < 2; ++j) {
            f32x4 linv;
#pragma unroll
            for (int r = 0; r < 4; ++r) linv[r] = 1.f / fmaxf(Lacc[j][r], 1e-30f);
#pragma unroll
            for (int nt = 0; nt < 4; ++nt)
#pragma unroll
                for (int r = 0; r < 4; ++r) {
                    const int qg2 = (qt << 6) + (qw << 5) + j * 16 + (quad << 2) + r;
                    const u32 u =
                        __builtin_bit_cast(u32, o[j][nt][r] * linv[r]) + 0x8000u;
                    Out[(size_t)(b * T_ + qg2) * D_ + (h << 6) + nt * 16 + l15]
                        = (u16)(u >> 16);
                }
        }
    }
}

extern "C" void kernel_launch(void* const* d_in, const int* in_sizes, int n_in,
                              void* d_out, int out_size, void* d_ws, size_t ws_size,
                              hipStream_t stream)
{
    const float* x  = (const float*)d_in[0];
    // d_in[1]: causal mask (deterministic tril) — applied analytically.
    const float* Wq = (const float*)d_in[2];
    const float* bq = (const float*)d_in[3];
    const float* Wk = (const float*)d_in[4];
    const float* bk = (const float*)d_in[5];
    const float* Wv = (const float*)d_in[6];
    const float* bv = (const float*)d_in[7];
    const float* Wo = (const float*)d_in[8];
    const float* bo = (const float*)d_in[9];
    float* out = (float*)d_out;

    const size_t M1 = (size_t)1 << 20;
    u16* wsu = (u16*)d_ws;
    u16* xb  = wsu;             // 4M elems (B,T,D) bf16
    u16* wqb = wsu + 4 * M1;
    u16* wkb = wsu + 5 * M1;
    u16* wvb = wsu + 6 * M1;
    u16* wob = wsu + 7 * M1;
    u16* Qb  = wsu + 8 * M1;    // (B,H,T,HD) bf16, pre-scaled
    u16* Kb  = wsu + 12 * M1;   // (B,H,T,HD) bf16
    u16* Vtb = wsu + 16 * M1;   // (B,H,HD,T) bf16
    u16* AOb = wsu + 20 * M1;   // (B,T,D) bf16

    to_bf16<<<4096, 256, 0, stream>>>(x, Wq, Wk, Wv, Wo, wsu);

    gemm_qkv<<<192, 512, 0, stream>>>(xb, wqb, wkb, wvb, bq, bk, bv, Qb, Kb, Vtb);

    dim3 ga(B_ * H_, T_ / 64);               // (32, 32) single q-tiles, LPT order
    attn_mfma<<<ga, 256, 0, stream>>>(Qb, Kb, Vtb, AOb);

    gemm_out<<<256, 256, 0, stream>>>(AOb, wob, bo, out);
}

// Round 11
// 186.148 us; speedup vs baseline: 1.0176x; 1.0176x over previous
//
#include <hip/hip_runtime.h>

#define B_ 2
#define H_ 16
#define T_ 2048
#define D_ 1024
#define HD_ 64
#define NEG_HUGE (-3.402823466e38f)
#define QSCALE 0.18033688011112042f   // 0.125 * log2(e), folded into Q projection

typedef unsigned short u16;
typedef unsigned int u32;
typedef __attribute__((ext_vector_type(8))) short bf16x8;
typedef __attribute__((ext_vector_type(4))) float f32x4;
typedef __attribute__((ext_vector_type(4))) u32 u32x4;

typedef const __attribute__((address_space(1))) void* gas_t;
typedef __attribute__((address_space(3))) void* las_t;

__device__ __forceinline__ u16 f2bf(float f) {
    u32 u = __builtin_bit_cast(u32, f);
    u += 0x7FFFu + ((u >> 16) & 1u);      // RNE
    return (u16)(u >> 16);
}

// pack 2 f32 -> 2 bf16 (round-half-up) in one v_perm_b32
__device__ __forceinline__ u32 pk2bf(float f0, float f1) {
    const u32 a0 = __builtin_bit_cast(u32, f0) + 0x8000u;
    const u32 a1 = __builtin_bit_cast(u32, f1) + 0x8000u;
    return __builtin_amdgcn_perm(a1, a0, 0x07060302u);
}

__device__ __forceinline__ uint2 pk4bf(f32x4 a) {
    uint2 r;
    r.x = pk2bf(a[0], a[1]);
    r.y = pk2bf(a[2], a[3]);
    return r;
}

__device__ __forceinline__ f32x4 mfma16(bf16x8 a, bf16x8 b, f32x4 c) {
    return __builtin_amdgcn_mfma_f32_16x16x32_bf16(a, b, c, 0, 0, 0);
}

// fp32 -> bf16 cast of concat [x(4M) | Wq(1M) | Wk(1M) | Wv(1M) | Wo(1M)] elems
__global__ __launch_bounds__(256) void to_bf16(
    const float* __restrict__ x,  const float* __restrict__ wq,
    const float* __restrict__ wk, const float* __restrict__ wv,
    const float* __restrict__ wo, u16* __restrict__ dst)
{
    const size_t g = ((size_t)blockIdx.x * 256 + threadIdx.x) * 8;
    const float* src; size_t off;
    if      (g < (size_t)(4u << 20)) { src = x;  off = g; }
    else if (g < (size_t)(5u << 20)) { src = wq; off = g - (size_t)(4u << 20); }
    else if (g < (size_t)(6u << 20)) { src = wk; off = g - (size_t)(5u << 20); }
    else if (g < (size_t)(7u << 20)) { src = wv; off = g - (size_t)(6u << 20); }
    else                             { src = wo; off = g - (size_t)(7u << 20); }
    const float4 a = *(const float4*)&src[off];
    const float4 b = *(const float4*)&src[off + 4];
    ushort4 lo = make_ushort4(f2bf(a.x), f2bf(a.y), f2bf(a.z), f2bf(a.w));
    ushort4 hi = make_ushort4(f2bf(b.x), f2bf(b.y), f2bf(b.z), f2bf(b.w));
    *(ushort4*)&dst[g]     = lo;
    *(ushort4*)&dst[g + 4] = hi;
}

// 128x128x1024 bf16 MFMA core with REGISTER-prefetch staging (kept for
// gemm_out at 4 blocks/CU, where cross-barrier in-flight loads win).
__device__ __forceinline__ void gemm128_core(
    const u16* __restrict__ P0, const u16* __restrict__ P1,
    const int m0, const int n0, u16* As, u16* Bs, f32x4 (&acc)[4][4])
{
    const int tid  = threadIdx.x;
    const int lane = tid & 63;
    const int quad = lane >> 4;
    const int l15  = lane & 15;
    const int w    = tid >> 6;
    const int wm   = (w >> 1) << 6;
    const int wn   = (w & 1) << 6;
    const int swz  = l15 & 7;

    size_t aoff[4], boff[4];
    int    loff[4];
#pragma unroll
    for (int i = 0; i < 4; ++i) {
        const int slot = i * 256 + tid;
        const int r = slot >> 3, c = slot & 7;
        const int gc = (c ^ (r & 7)) << 3;
        aoff[i] = (size_t)(m0 + r) * D_ + gc;
        boff[i] = (size_t)(n0 + r) * D_ + gc;
        loff[i] = slot * 8;
    }
    int rowA[4], rowB[4];
#pragma unroll
    for (int i = 0; i < 4; ++i) {
        rowA[i] = (wm + i * 16 + l15) * 64;
        rowB[i] = (wn + i * 16 + l15) * 64;
    }

    bf16x8 pa[4], pb[4];
#pragma unroll
    for (int i = 0; i < 4; ++i) {
        pa[i] = *(const bf16x8*)&P0[aoff[i]];
        pb[i] = *(const bf16x8*)&P1[boff[i]];
    }

    for (int k0 = 0; k0 < D_; k0 += 64) {
        __syncthreads();                  // prev compute done reading LDS
#pragma unroll
        for (int i = 0; i < 4; ++i) {
            *(bf16x8*)&As[loff[i]] = pa[i];
            *(bf16x8*)&Bs[loff[i]] = pb[i];
        }
        if (k0 + 64 < D_) {
            const int kn = k0 + 64;
#pragma unroll
            for (int i = 0; i < 4; ++i) {
                pa[i] = *(const bf16x8*)&P0[aoff[i] + kn];
                pb[i] = *(const bf16x8*)&P1[boff[i] + kn];
            }
        }
        __syncthreads();                  // staging visible; prefetch in flight
#pragma unroll
        for (int s = 0; s < 2; ++s) {
            const int ch = (((s << 2) + quad) ^ swz) << 3;
            bf16x8 am[4], bm[4];
#pragma unroll
            for (int mi = 0; mi < 4; ++mi) am[mi] = *(const bf16x8*)&As[rowA[mi] + ch];
#pragma unroll
            for (int ni = 0; ni < 4; ++ni) bm[ni] = *(const bf16x8*)&Bs[rowB[ni] + ch];
#pragma unroll
            for (int mi = 0; mi < 4; ++mi)
#pragma unroll
                for (int ni = 0; ni < 4; ++ni)
                    acc[mi][ni] = mfma16(am[mi], bm[ni], acc[mi][ni]);
        }
    }
}

// Fused QKV projection as ONE 3072x4096x1024 GEMM. 256^2 tiles, 512 thr
// (8 waves 2Mx4N), 128 KiB LDS double-buffered by K-tile, global_load_lds
// width-16 staging with COUNTED vmcnt (never drained to 0 mid-loop) and
// raw s_barrier. Stage of K-tile t+2 issues mid-iter t, waited end of
// iter t+1. LDS XOR swizzle via pre-swizzled global source.
__global__ __launch_bounds__(512, 2) void gemm_qkv(
    const u16* __restrict__ xb,
    const u16* __restrict__ Wqb, const u16* __restrict__ Wkb, const u16* __restrict__ Wvb,
    const float* __restrict__ bq, const float* __restrict__ bk, const float* __restrict__ bv,
    u16* __restrict__ Qb, u16* __restrict__ Kb, u16* __restrict__ Vtb)
{
    __shared__ u16 lds[65536];            // 128 KiB: [A0|A1|B0|B1] 16K elems each
    const int tid  = threadIdx.x;
    const int lane = tid & 63;
    const int quad = lane >> 4;
    const int l15  = lane & 15;
    const int w    = tid >> 6;
    const int wr   = w >> 2;              // 0..1 (M dir)
    const int wc   = w & 3;               // 0..3 (N dir)
    const int swz7 = l15 & 7;

    const int L  = blockIdx.x;
    const int wg = (L & 7) * 24 + (L >> 3);   // bijective XCD swizzle (192%8==0)
    const int ftile = wg >> 4;            // 0..11
    const int ttile = wg & 15;            // 0..15
    const int z  = ftile >> 2;            // 0:Q 1:K 2:V
    const int fb = (ftile & 3) << 8;      // feature base within 1024

    const u16* PA; const u16* PB;
    int Ra, Rb;
    if (z == 0)      { PA = Wqb; PB = xb;  Ra = fb;         Rb = ttile << 8; }
    else if (z == 1) { PA = Wkb; PB = xb;  Ra = fb;         Rb = ttile << 8; }
    else             { PA = xb;  PB = Wvb; Ra = ttile << 8; Rb = fb;         }

    // staging addresses: load i covers rows [i*64, i*64+64) of the 256-row side
    const int rr  = tid >> 3;
    const int cc8 = ((tid & 7) ^ (rr & 7)) << 3;   // pre-swizzled source chunk
    size_t srcA[4], srcB[4];
#pragma unroll
    for (int i = 0; i < 4; ++i) {
        srcA[i] = (size_t)(Ra + i * 64 + rr) * D_ + cc8;
        srcB[i] = (size_t)(Rb + i * 64 + rr) * D_ + cc8;
    }
    const int dstT = tid * 8;             // linear LDS dest (elems), lane*16B

#define QKV_STAGE(p, kt) do {                                               \
    const size_t ko_ = (size_t)(kt) * 64;                                   \
    _Pragma("unroll")                                                       \
    for (int i_ = 0; i_ < 4; ++i_)                                          \
        __builtin_amdgcn_global_load_lds((gas_t)(PA + srcA[i_] + ko_),      \
            (las_t)&lds[((p) << 14) + i_ * 4096 + dstT], 16, 0, 0);         \
    _Pragma("unroll")                                                       \
    for (int i_ = 0; i_ < 4; ++i_)                                          \
        __builtin_amdgcn_global_load_lds((gas_t)(PB + srcB[i_] + ko_),      \
            (las_t)&lds[32768 + ((p) << 14) + i_ * 4096 + dstT], 16, 0, 0); \
} while (0)

    // fragment read bases (r&7 == l15&7 for all mi/ni since 16|step)
    const int baseA = ((wr << 7) + l15) * 64;
    const int baseB = 32768 + ((wc << 6) + l15) * 64;
    const int cs0 = (quad ^ swz7) << 3;
    const int cs1 = ((quad + 4) ^ swz7) << 3;

    f32x4 acc[8][4];
#pragma unroll
    for (int i = 0; i < 8; ++i)
#pragma unroll
        for (int j = 0; j < 4; ++j) acc[i][j] = (f32x4){0.f, 0.f, 0.f, 0.f};

    QKV_STAGE(0, 0);
    QKV_STAGE(1, 1);
    asm volatile("s_waitcnt vmcnt(8)" ::: "memory");   // K-tile 0 landed
    __builtin_amdgcn_s_barrier();

    for (int kt = 0; kt < 16; ++kt) {
        const int pO = (kt & 1) << 14;
        bf16x8 bfr[4][2], afr[4][2];
#pragma unroll
        for (int ni = 0; ni < 4; ++ni) {
            bfr[ni][0] = *(const bf16x8*)&lds[pO + baseB + ni * 1024 + cs0];
            bfr[ni][1] = *(const bf16x8*)&lds[pO + baseB + ni * 1024 + cs1];
        }
#pragma unroll
        for (int mi = 0; mi < 4; ++mi) {
            afr[mi][0] = *(const bf16x8*)&lds[pO + baseA + mi * 1024 + cs0];
            afr[mi][1] = *(const bf16x8*)&lds[pO + baseA + mi * 1024 + cs1];
        }
        __builtin_amdgcn_s_setprio(1);
#pragma unroll
        for (int mi = 0; mi < 4; ++mi)
#pragma unroll
            for (int ni = 0; ni < 4; ++ni) {
                acc[mi][ni] = mfma16(afr[mi][0], bfr[ni][0], acc[mi][ni]);
                acc[mi][ni] = mfma16(afr[mi][1], bfr[ni][1], acc[mi][ni]);
            }
        __builtin_amdgcn_s_setprio(0);
#pragma unroll
        for (int mi = 0; mi < 4; ++mi) {
            afr[mi][0] = *(const bf16x8*)&lds[pO + baseA + (mi + 4) * 1024 + cs0];
            afr[mi][1] = *(const bf16x8*)&lds[pO + baseA + (mi + 4) * 1024 + cs1];
        }
        asm volatile("s_waitcnt lgkmcnt(0)" ::: "memory");  // all my LDS reads done
        __builtin_amdgcn_sched_barrier(0);
        __builtin_amdgcn_s_barrier();                       // buf(kt&1) free
        __builtin_amdgcn_sched_barrier(0);
        if (kt + 2 < 16) QKV_STAGE(kt & 1, kt + 2);         // overwrite freed buf
        __builtin_amdgcn_s_setprio(1);
#pragma unroll
        for (int mi = 0; mi < 4; ++mi)
#pragma unroll
            for (int ni = 0; ni < 4; ++ni) {
                acc[mi + 4][ni] = mfma16(afr[mi][0], bfr[ni][0], acc[mi + 4][ni]);
                acc[mi + 4][ni] = mfma16(afr[mi][1], bfr[ni][1], acc[mi + 4][ni]);
            }
        __builtin_amdgcn_s_setprio(0);
        if (kt < 14) asm volatile("s_waitcnt vmcnt(8)" ::: "memory"); // tile kt+1 in
        else         asm volatile("s_waitcnt vmcnt(0)" ::: "memory"); // tail drain
        __builtin_amdgcn_sched_barrier(0);
        __builtin_amdgcn_s_barrier();                       // buf(kt+1 & 1) ready
    }
#undef QKV_STAGE

    __syncthreads();                      // LDS reusable as epilogue scratch
    u16* scr = &lds[w * 8192];            // 16 KB per wave
    const int pq   = quad >> 1;
    const int psub = (quad & 1) << 2;

    if (z < 2) {
        // wave tile: f [fb+wr*128, +128) (2 heads), t [ttile*256+wc*64, +64)
        const float* bias = (z == 0) ? bq : bk;
        const float  CF   = (z == 0) ? QSCALE : 1.f;
        u16*         Cq   = (z == 0) ? Qb : Kb;
        const int fbw = fb + (wr << 7);
        const int tbw = (ttile << 8) + (wc << 6);
        // scratch [t 64][f 128], 16-chunk XOR swizzle
#pragma unroll
        for (int mi = 0; mi < 8; ++mi) {
            const float4 bi = *(const float4*)&bias[fbw + mi * 16 + (quad << 2)];
            const int c = (mi << 1) + pq;
#pragma unroll
            for (int ni = 0; ni < 4; ++ni) {
                const int tl = ni * 16 + l15;
                f32x4 a = acc[mi][ni];
                f32x4 v = { (a[0] + bi.x) * CF, (a[1] + bi.y) * CF,
                            (a[2] + bi.z) * CF, (a[3] + bi.w) * CF };
                *(uint2*)&scr[tl * 128 + ((c ^ (tl & 15)) << 3) + psub] = pk4bf(v);
            }
        }
        __asm__ volatile("s_waitcnt lgkmcnt(0)" ::: "memory");
        const int hb = fbw >> 6;
#pragma unroll
        for (int e = 0; e < 16; ++e) {
            const int tl = (e << 2) + (lane >> 4);
            const int c  = lane & 15;
            bf16x8 v = *(const bf16x8*)&scr[tl * 128 + ((c ^ (tl & 15)) << 3)];
            const int tg = tbw + tl;
            const int bb = tg >> 11, t0 = tg & 2047;
            *(bf16x8*)&Cq[((size_t)((bb << 4) + hb + (c >> 3)) * T_ + t0) * HD_ +
                          ((c & 7) << 3)] = v;
        }
    } else {
        // V: M=t, N=f. wave tile: t [ttile*256+wr*128, +128), f [fb+wc*64, +64)
        const int fvw = fb + (wc << 6);
        const int h   = fvw >> 6;
        const int tbw = (ttile << 8) + (wr << 7);
        // scratch [hd 64][t 128]
#pragma unroll
        for (int ni = 0; ni < 4; ++ni) {
            const int hdrow = ni * 16 + l15;
            const float bi = bv[fvw + ni * 16 + l15];
            const int sw = hdrow & 15;
#pragma unroll
            for (int mi = 0; mi < 8; ++mi) {
                f32x4 a = acc[mi][ni];
                f32x4 v = { a[0] + bi, a[1] + bi, a[2] + bi, a[3] + bi };
                const int c = (mi << 1) + pq;
                *(uint2*)&scr[hdrow * 128 + ((c ^ sw) << 3) + psub] = pk4bf(v);
            }
        }
        __asm__ volatile("s_waitcnt lgkmcnt(0)" ::: "memory");
#pragma unroll
        for (int e = 0; e < 16; ++e) {
            const int hdl = (e << 2) + (lane >> 4);
            const int c   = lane & 15;
            bf16x8 v = *(const bf16x8*)&scr[hdl * 128 + ((c ^ (hdl & 15)) << 3)];
            const int tg = tbw + (c << 3);
            const int bb = tg >> 11, t0 = tg & 2047;
            *(bf16x8*)&Vtb[((size_t)((bb << 4) + h) * HD_ + hdl) * T_ + t0] = v;
        }
    }
}

// Output projection: A bf16 (B,T,D), W bf16, C fp32 + bias. XCD-swizzled.
// Reg-staged 128^2 core (r4-proven; the 1-block/CU pipelined variant
// regressed in r5 — 1 wave/SIMD lockstep has no TLP to hide latency).
__global__ __launch_bounds__(256) void gemm_out(
    const u16* __restrict__ Ab, const u16* __restrict__ Wob,
    const float* __restrict__ bo, float* __restrict__ C)
{
    __shared__ u16 As[128 * 64];
    __shared__ u16 Bs[128 * 64];
    const int L   = blockIdx.x;
    const int xcd = L & 7;
    const int kk  = L >> 3;               // 0..31
    const int tt  = (xcd << 2) + (kk & 3);
    const int ft  = kk >> 2;              // 0..7
    const int m0  = tt << 7;
    const int n0  = ft << 7;

    f32x4 acc[4][4];
#pragma unroll
    for (int i = 0; i < 4; ++i)
#pragma unroll
        for (int j = 0; j < 4; ++j) acc[i][j] = (f32x4){0.f, 0.f, 0.f, 0.f};

    gemm128_core(Ab, Wob, m0, n0, As, Bs, acc);

    const int tid  = threadIdx.x;
    const int lane = tid & 63;
    const int quad = lane >> 4;
    const int l15  = lane & 15;
    const int w    = tid >> 6;
    const int wm   = (w >> 1) << 6;
    const int wn   = (w & 1) << 6;

    float bi[4];
#pragma unroll
    for (int ni = 0; ni < 4; ++ni) bi[ni] = bo[n0 + wn + ni * 16 + l15];

#pragma unroll
    for (int mi = 0; mi < 4; ++mi) {
        const int m = m0 + wm + mi * 16 + (quad << 2);
#pragma unroll
        for (int r = 0; r < 4; ++r)
#pragma unroll
            for (int ni = 0; ni < 4; ++ni)
                C[(size_t)(m + r) * D_ + n0 + wn + ni * 16 + l15] = acc[mi][ni][r] + bi[ni];
    }
}

// MFMA flash attention, causal, 128-key pipelined tiles, MAX-FREE softmax
// (base-2 scores, scale folded into Q). Grid (B*H, 32), one 64-row q-tile
// per block, LPT order (longest tiles dispatch first). P stays in
// registers via permlane quad-transpose. Single-buffer 32 KB K/V staging
// with register prefetch in flight across both barriers.
// Session-mapped nulls: occupancy (r3), dbuf/barrier-count (r7),
// bank-conflicts (r7), tail-peel (r8), pack-VALU (r9), 2x2 q/key wave
// split & LDS traffic (r10). Residual bound: per-iter dependent chain.
__global__ __launch_bounds__(256) void attn_mfma(
    const u16* __restrict__ Qg, const u16* __restrict__ Kg,
    const u16* __restrict__ Vtg, u16* __restrict__ Out)
{
    __shared__ u16 Ks[128 * 64];     // [key][hd], XOR-swizzled
    __shared__ u16 Vs[64 * 128];     // [hd][key], XOR-swizzled
    const int tid  = threadIdx.x;
    const int w    = tid >> 6;
    const int lane = tid & 63;
    const int quad = lane >> 4;
    const int l15  = lane & 15;
    const int bh   = blockIdx.x;
    const int qt   = 31 - (int)blockIdx.y;         // longest first
    const size_t base = (size_t)bh * (T_ * HD_);

    int lK[4], lV[4];
    size_t gK[4], gV[4];
#pragma unroll
    for (int i = 0; i < 4; ++i) {
        const int slot = i * 256 + tid;
        const int rk = slot >> 3, ck = slot & 7;
        lK[i] = rk * 64 + ((ck ^ (rk & 7)) << 3);
        gK[i] = base + (size_t)rk * HD_ + ck * 8;
        const int rv = slot >> 4, cv = slot & 15;
        lV[i] = rv * 128 + ((cv ^ (rv & 15)) << 3);
        gV[i] = base + (size_t)rv * T_ + cv * 8;
    }

    bf16x8 ones;
#pragma unroll
    for (int i = 0; i < 8; ++i) ones[i] = (short)0x3F80;   // bf16 1.0

    const int swz7 = l15 & 7;
    const int b = bh >> 4, h = bh & 15;

    const int qloc = (w << 4) + l15;
    const int qrow = (qt << 6) + qloc;
    const bf16x8 qf0 = *(const bf16x8*)&Qg[base + (size_t)qrow * HD_ + quad * 8];
    const bf16x8 qf1 = *(const bf16x8*)&Qg[base + (size_t)qrow * HD_ + 32 + quad * 8];

    f32x4 o[4];
#pragma unroll
    for (int nt = 0; nt < 4; ++nt) o[nt] = (f32x4){0.f, 0.f, 0.f, 0.f};
    f32x4 Lacc = (f32x4){0.f, 0.f, 0.f, 0.f};

    const int nIter = (qt + 2) >> 1;
    bf16x8 kreg[4], vreg[4];
#pragma unroll
    for (int i = 0; i < 4; ++i) {
        kreg[i] = *(const bf16x8*)&Kg[gK[i]];
        vreg[i] = *(const bf16x8*)&Vtg[gV[i]];
    }

    for (int it = 0; it < nIter; ++it) {
        __syncthreads();
#pragma unroll
        for (int i = 0; i < 4; ++i) {
            *(bf16x8*)&Ks[lK[i]] = kreg[i];
            *(bf16x8*)&Vs[lV[i]] = vreg[i];
        }
        if (it + 1 < nIter) {
            const int koff = (it + 1) << 7;
#pragma unroll
            for (int i = 0; i < 4; ++i) {
                kreg[i] = *(const bf16x8*)&Kg[gK[i] + (size_t)koff * HD_];
                vreg[i] = *(const bf16x8*)&Vtg[gV[i] + koff];
            }
        }
        __syncthreads();

        f32x4 st[8];
#pragma unroll
        for (int t = 0; t < 8; ++t) {
            const int kr = (t * 16 + l15) * 64;
            const bf16x8 k0 = *(const bf16x8*)&Ks[kr + ((quad ^ swz7) << 3)];
            const bf16x8 k1 = *(const bf16x8*)&Ks[kr + (((quad + 4) ^ swz7) << 3)];
            f32x4 a = (f32x4){0.f, 0.f, 0.f, 0.f};
            a = mfma16(k0, qf0, a);
            a = mfma16(k1, qf1, a);
            st[t] = a;
        }

        if (it == nIter - 1) {
            const int koff = it << 7;
#pragma unroll
            for (int t = 0; t < 8; ++t)
#pragma unroll
                for (int r = 0; r < 4; ++r) {
                    const int kg = koff + t * 16 + (quad << 2) + r;
                    if (kg > qrow) st[t][r] = NEG_HUGE;
                }
        }

#pragma unroll
        for (int t = 0; t < 8; ++t)
#pragma unroll
            for (int r = 0; r < 4; ++r) st[t][r] = __builtin_amdgcn_exp2f(st[t][r]);

        // in-register quad-transpose: scores -> PV A-fragments
        bf16x8 pf[4];
#pragma unroll
        for (int kq = 0; kq < 4; ++kq) {
            u32 c00 = pk2bf(st[2 * kq][0],     st[2 * kq][1]);
            u32 c01 = pk2bf(st[2 * kq][2],     st[2 * kq][3]);
            u32 c10 = pk2bf(st[2 * kq + 1][0], st[2 * kq + 1][1]);
            u32 c11 = pk2bf(st[2 * kq + 1][2], st[2 * kq + 1][3]);
            asm("v_permlane32_swap_b32 %0, %1" : "+v"(c00), "+v"(c10));
            asm("v_permlane16_swap_b32 %0, %1" : "+v"(c00), "+v"(c10));
            asm("v_permlane32_swap_b32 %0, %1" : "+v"(c01), "+v"(c11));
            asm("v_permlane16_swap_b32 %0, %1" : "+v"(c01), "+v"(c11));
            u32x4 dw;
            dw[0] = c00; dw[1] = c01; dw[2] = c10; dw[3] = c11;
            pf[kq] = __builtin_bit_cast(bf16x8, dw);
        }

        __builtin_amdgcn_s_setprio(1);
#pragma unroll
        for (int nt = 0; nt < 4; ++nt) {
            f32x4 oo = o[nt];
            const int vr = (nt * 16 + l15) * 128;
#pragma unroll
            for (int kq = 0; kq < 4; ++kq) {
                const bf16x8 vf = *(const bf16x8*)&Vs[vr + ((((kq << 2) + quad) ^ l15) << 3)];
                oo = mfma16(pf[kq], vf, oo);
            }
            o[nt] = oo;
        }
#pragma unroll
        for (int kq = 0; kq < 4; ++kq)
            Lacc = mfma16(pf[kq], ones, Lacc);
        __builtin_amdgcn_s_setprio(0);
    }

    f32x4 linv;
#pragma unroll
    for (int r = 0; r < 4; ++r) linv[r] = 1.f / fmaxf(Lacc[r], 1e-30f);

#pragma unroll
    for (int nt = 0; nt < 4; ++nt)
#pragma unroll
        for (int r = 0; r < 4; ++r) {
            const int qg2 = (qt << 6) + (w << 4) + (quad << 2) + r;
            const u32 u = __builtin_bit_cast(u32, o[nt][r] * linv[r]) + 0x8000u;
            Out[(size_t)(b * T_ + qg2) * D_ + (h << 6) + nt * 16 + l15] = (u16)(u >> 16);
        }
}

extern "C" void kernel_launch(void* const* d_in, const int* in_sizes, int n_in,
                              void* d_out, int out_size, void* d_ws, size_t ws_size,
                              hipStream_t stream)
{
    const float* x  = (const float*)d_in[0];
    // d_in[1]: causal mask (deterministic tril) — applied analytically.
    const float* Wq = (const float*)d_in[2];
    const float* bq = (const float*)d_in[3];
    const float* Wk = (const float*)d_in[4];
    const float* bk = (const float*)d_in[5];
    const float* Wv = (const float*)d_in[6];
    const float* bv = (const float*)d_in[7];
    const float* Wo = (const float*)d_in[8];
    const float* bo = (const float*)d_in[9];
    float* out = (float*)d_out;

    const size_t M1 = (size_t)1 << 20;
    u16* wsu = (u16*)d_ws;
    u16* xb  = wsu;             // 4M elems (B,T,D) bf16
    u16* wqb = wsu + 4 * M1;
    u16* wkb = wsu + 5 * M1;
    u16* wvb = wsu + 6 * M1;
    u16* wob = wsu + 7 * M1;
    u16* Qb  = wsu + 8 * M1;    // (B,H,T,HD) bf16, pre-scaled
    u16* Kb  = wsu + 12 * M1;   // (B,H,T,HD) bf16
    u16* Vtb = wsu + 16 * M1;   // (B,H,HD,T) bf16
    u16* AOb = wsu + 20 * M1;   // (B,T,D) bf16

    to_bf16<<<4096, 256, 0, stream>>>(x, Wq, Wk, Wv, Wo, wsu);

    gemm_qkv<<<192, 512, 0, stream>>>(xb, wqb, wkb, wvb, bq, bk, bv, Qb, Kb, Vtb);

    dim3 ga(B_ * H_, T_ / 64);               // (32, 32) single q-tiles, LPT order
    attn_mfma<<<ga, 256, 0, stream>>>(Qb, Kb, Vtb, AOb);

    gemm_out<<<256, 256, 0, stream>>>(AOb, wob, bo, out);
}